// Round 2
// baseline (1484.003 us; speedup 1.0000x reference)
//
#include <hip/hip_runtime.h>
#include <hip/hip_bf16.h>

// SparseLinear: out[8192,128] = sum over COO entries (r,c,v): out[r,:] += v * x[c,:]
// R2 strategy: 512-bucket radix partition (16 rows/bucket), then per-bucket SpMM
// with coalesced record loads + v_readlane broadcast + LDS fp32 accumulation.

#define M_ROWS 8192
#define B_COLS 128
#define NB 512            // buckets (row >> 4)
#define ROWS_PER_B 16
#define NPART 256         // partition/hist blocks
#define DTHREADS 512      // spmm block threads (8 waves)

// ---------------- Kernel A: per-block bucket histogram (no global atomics) ----
__global__ void __launch_bounds__(256) bucket_hist_kernel(const int* __restrict__ rows, int nnz,
                                                          int chunk, int* __restrict__ perHist) {
    __shared__ int hist[NB];
    int t = threadIdx.x, g = blockIdx.x;
    for (int i = t; i < NB; i += 256) hist[i] = 0;
    __syncthreads();
    int s = g * chunk;
    int e = min(s + chunk, nnz);
    for (int i = s + t; i < e; i += 256) {
        atomicAdd(&hist[rows[i] >> 4], 1);
    }
    __syncthreads();
    // perHist layout: [bucket][block] so the scan kernel reads contiguously
    for (int b = t; b < NB; b += 256) perHist[b * NPART + g] = hist[b];
}

// ---------------- Kernel B: bucket totals + exclusive scan ----------------
__global__ void __launch_bounds__(512) bucket_scan_kernel(const int* __restrict__ perHist, int nnz,
                                                          int* __restrict__ bucketStart,
                                                          int* __restrict__ cursor) {
    __shared__ int totals[NB];
    __shared__ int gbase[64];
    int b = threadIdx.x;  // 0..511, one bucket per thread
    int s = 0;
    const int* p = perHist + b * NPART;
    for (int g = 0; g < NPART; ++g) s += p[g];
    totals[b] = s;
    __syncthreads();
    if (b < 64) {
        int gs = 0;
#pragma unroll
        for (int k = 0; k < 8; ++k) gs += totals[b * 8 + k];
        gbase[b] = gs;
    }
    __syncthreads();
    if (b == 0) {
        int acc = 0;
        for (int i = 0; i < 64; ++i) { int c = gbase[i]; gbase[i] = acc; acc += c; }
    }
    __syncthreads();
    int off = gbase[b >> 3];
    for (int k = (b & ~7); k < b; ++k) off += totals[k];
    bucketStart[b] = off;
    cursor[b] = off;
    if (b == 0) bucketStart[NB] = nnz;
}

// ---------------- Kernel C: partition entries into bucket segments ----------
__global__ void __launch_bounds__(256) partition_kernel(const int* __restrict__ rows,
                                                        const int* __restrict__ cols,
                                                        const float* __restrict__ vals, int nnz, int chunk,
                                                        const int* __restrict__ perHist,
                                                        int* __restrict__ cursor,
                                                        int2* __restrict__ pairs) {
    __shared__ int cur[NB];
    int t = threadIdx.x, g = blockIdx.x;
    // one global atomic per (block, nonempty bucket) reserves a contiguous range
    for (int b = t; b < NB; b += 256) {
        int cnt = perHist[b * NPART + g];
        cur[b] = cnt ? atomicAdd(&cursor[b], cnt) : 0;
    }
    __syncthreads();
    int s = g * chunk;
    int e = min(s + chunk, nnz);
    for (int i = s + t; i < e; i += 256) {
        int r = rows[i];
        int c = cols[i];
        float v = vals[i];
        int b = r >> 4;
        int pos = atomicAdd(&cur[b], 1);           // LDS atomic
        pairs[pos] = make_int2((r << 13) | c, __float_as_int(v));
    }
}

// ---------------- Kernel D: per-bucket SpMM --------------------------------
// Block = 1 bucket (16 rows). 8 waves; each wave loads 64 records coalesced,
// broadcasts via readlane, gathers 512B of x, accumulates into LDS.
// Deinterleaved accE/accO layout: lane l -> word (row*64 + l), stride-1 -> no
// bank conflicts on ds_add_f32 (float2 layout would be 4-way conflicted).
__global__ void __launch_bounds__(DTHREADS) spmm_bucket_kernel(const int2* __restrict__ pairs,
                                                               const int* __restrict__ bucketStart,
                                                               const float* __restrict__ x,
                                                               float* __restrict__ out) {
    __shared__ float accE[ROWS_PER_B * 64];  // even cols: accE[r*64 + l] = out[r][2l]
    __shared__ float accO[ROWS_PER_B * 64];  // odd  cols: accO[r*64 + l] = out[r][2l+1]
    int t = threadIdx.x;
    int bkt = blockIdx.x;
    for (int i = t; i < ROWS_PER_B * 64; i += DTHREADS) { accE[i] = 0.f; accO[i] = 0.f; }
    __syncthreads();

    int segS = bucketStart[bkt];
    int n = bucketStart[bkt + 1] - segS;
    int wave = t >> 6, lane = t & 63;

    for (int base = wave * 64; base < n; base += (DTHREADS / 64) * 64) {
        int idx = base + lane;
        int2 rec = (idx < n) ? pairs[segS + idx] : make_int2(0, 0);
        int cnt = min(n - base, 64);
#pragma unroll 4
        for (int j = 0; j < cnt; ++j) {
            int rc = __builtin_amdgcn_readlane(rec.x, j);
            float v = __int_as_float(__builtin_amdgcn_readlane(rec.y, j));
            int col = rc & 8191;
            int rowLow = (rc >> 13) & 15;
            const float2 xv = *(const float2*)(x + col * B_COLS + 2 * lane);
            atomicAdd(&accE[rowLow * 64 + lane], v * xv.x);
            atomicAdd(&accO[rowLow * 64 + lane], v * xv.y);
        }
    }
    __syncthreads();

    for (int k = t; k < ROWS_PER_B * 64; k += DTHREADS) {
        int r = k >> 6, l = k & 63;
        float2 o = make_float2(accE[k], accO[k]);
        *(float2*)(out + ((size_t)(bkt * ROWS_PER_B + r)) * B_COLS + 2 * l) = o;
    }
}

// ---------------- Fallback if workspace too small ---------------------------
__global__ void atomic_spmm_kernel(const int* __restrict__ rows, const int* __restrict__ cols,
                                   const float* __restrict__ vals, int nnz,
                                   const float* __restrict__ x, float* __restrict__ out) {
    long long tid = (long long)blockIdx.x * blockDim.x + threadIdx.x;
    int e = (int)(tid >> 5);
    int g = (int)(tid & 31);
    if (e < nnz) {
        int r = rows[e], c = cols[e];
        float v = vals[e];
        const float4 xv = *(const float4*)(x + (size_t)c * B_COLS + g * 4);
        float* o = out + (size_t)r * B_COLS + g * 4;
        atomicAdd(o + 0, v * xv.x);
        atomicAdd(o + 1, v * xv.y);
        atomicAdd(o + 2, v * xv.z);
        atomicAdd(o + 3, v * xv.w);
    }
}

extern "C" void kernel_launch(void* const* d_in, const int* in_sizes, int n_in,
                              void* d_out, int out_size, void* d_ws, size_t ws_size,
                              hipStream_t stream) {
    const int*   ids  = (const int*)d_in[0];
    const int    nnz  = in_sizes[0] / 2;
    const int*   rows = ids;
    const int*   cols = ids + nnz;
    const float* vals = (const float*)d_in[1];
    const float* x    = (const float*)d_in[2];
    float*       out  = (float*)d_out;

    // ws layout: perHist[NB*NPART] | bucketStart[NB+1] | cursor[NB] | pad | pairs[nnz] int2
    size_t ints_head = (size_t)NB * NPART + (NB + 1) + NB;
    ints_head = (ints_head + 1) & ~(size_t)1;  // 8B-align pairs
    size_t need = ints_head * 4 + (size_t)nnz * 8;

    if (ws_size >= need) {
        int*  perHist     = (int*)d_ws;
        int*  bucketStart = perHist + (size_t)NB * NPART;
        int*  cursor      = bucketStart + (NB + 1);
        int2* pairs       = (int2*)((int*)d_ws + ints_head);
        int   chunk       = (nnz + NPART - 1) / NPART;

        bucket_hist_kernel<<<NPART, 256, 0, stream>>>(rows, nnz, chunk, perHist);
        bucket_scan_kernel<<<1, 512, 0, stream>>>(perHist, nnz, bucketStart, cursor);
        partition_kernel<<<NPART, 256, 0, stream>>>(rows, cols, vals, nnz, chunk,
                                                    perHist, cursor, pairs);
        spmm_bucket_kernel<<<NB, DTHREADS, 0, stream>>>(pairs, bucketStart, x, out);
    } else {
        hipMemsetAsync(d_out, 0, (size_t)out_size * sizeof(float), stream);
        long long total = (long long)nnz * 32;
        atomic_spmm_kernel<<<(unsigned)((total + 255) / 256), 256, 0, stream>>>(rows, cols, vals, nnz, x, out);
    }
}

// Round 3
// 245.167 us; speedup vs baseline: 6.0530x; 6.0530x over previous
//
#include <hip/hip_runtime.h>
#include <hip/hip_bf16.h>

// SparseLinear: out[8192,128] = sum over COO entries (r,c,v): out[r,:] += v * x[c,:]
// R3: deterministic zero-global-atomic CSR build (LDS hist -> per-row chunk prefix ->
// row scan -> LDS-cursor partition), then wave-per-row SpMM with 2 entries/iter
// (half-wave float4 gathers) and register accumulation.

#define M_ROWS 8192
#define B_COLS 128

// ---------- A: per-chunk histogram (LDS atomics only) ----------------------
__global__ void __launch_bounds__(256) hist_kernel(const int* __restrict__ rows, int nnz,
                                                   int chunk, int* __restrict__ perHist) {
    __shared__ int h[M_ROWS];
    int t = threadIdx.x, g = blockIdx.x;
    for (int i = t; i < M_ROWS; i += 256) h[i] = 0;
    __syncthreads();
    int s = g * chunk, e = min(s + chunk, nnz);
    for (int i = s + t; i < e; i += 256) atomicAdd(&h[rows[i]], 1);
    __syncthreads();
    int* dst = perHist + (size_t)g * M_ROWS;
    for (int i = t; i < M_ROWS; i += 256) dst[i] = h[i];
}

// ---------- B1: per-row exclusive prefix across chunks, + row totals -------
// perHist layout [g][row]: reads/writes coalesced across threads (thread=row).
__global__ void __launch_bounds__(1024) rowscan_kernel(int* __restrict__ perHist, int ng,
                                                       int* __restrict__ rowTotal) {
    int row = blockIdx.x * 1024 + threadIdx.x;   // grid = M_ROWS/1024
    int acc = 0;
    for (int g = 0; g < ng; ++g) {
        int* p = perHist + (size_t)g * M_ROWS + row;
        int c = *p;
        *p = acc;
        acc += c;
    }
    rowTotal[row] = acc;
}

// ---------- B2: single-block exclusive scan of row totals -> rowStart ------
__global__ void __launch_bounds__(256) scan_kernel(const int* __restrict__ rowTotal,
                                                   int* __restrict__ rowStart, int nnz) {
    __shared__ int sums[256];
    __shared__ int offs[257];
    int t = threadIdx.x;
    int base = t * 32;
    int local[32];
    int s = 0;
#pragma unroll
    for (int j = 0; j < 32; ++j) { local[j] = rowTotal[base + j]; s += local[j]; }
    sums[t] = s;
    __syncthreads();
    if (t == 0) {
        int acc = 0;
        for (int i = 0; i < 256; ++i) { offs[i] = acc; acc += sums[i]; }
        offs[256] = acc;
    }
    __syncthreads();
    int acc = offs[t];
#pragma unroll
    for (int j = 0; j < 32; ++j) {
        int c = local[j];
        rowStart[base + j] = acc;
        acc += c;
    }
    if (t == 0) rowStart[M_ROWS] = nnz;
}

// ---------- C: partition entries to exact CSR slots (LDS cursors) ----------
__global__ void __launch_bounds__(256) partition_kernel(const int* __restrict__ rows,
                                                        const int* __restrict__ cols,
                                                        const float* __restrict__ vals,
                                                        int nnz, int chunk,
                                                        const int* __restrict__ perHist,
                                                        const int* __restrict__ rowStart,
                                                        int2* __restrict__ pairs) {
    __shared__ int cur[M_ROWS];
    int t = threadIdx.x, g = blockIdx.x;
    const int* ph = perHist + (size_t)g * M_ROWS;
    for (int i = t; i < M_ROWS; i += 256) cur[i] = rowStart[i] + ph[i];
    __syncthreads();
    int s = g * chunk, e = min(s + chunk, nnz);
    for (int i = s + t; i < e; i += 256) {
        int r = rows[i];
        int pos = atomicAdd(&cur[r], 1);        // LDS atomic only
        pairs[pos] = make_int2(cols[i], __float_as_int(vals[i]));
    }
}

// ---------- D: SpMM, wave per row, 2 entries/iter via half-waves -----------
__global__ void __launch_bounds__(256) spmm_csr_kernel(const int2* __restrict__ pairs,
                                                       const int* __restrict__ rowStart,
                                                       const float* __restrict__ x,
                                                       float* __restrict__ out) {
    int wave = threadIdx.x >> 6;
    int lane = threadIdx.x & 63;
    int row  = blockIdx.x * 4 + wave;
    int s = rowStart[row];
    int e = rowStart[row + 1];
    int half = lane >> 5;        // 0: entry i, 1: entry i+1
    int lh   = lane & 31;        // owns cols 4*lh .. 4*lh+3
    const float* xb = x + lh * 4;
    float4 acc = make_float4(0.f, 0.f, 0.f, 0.f);
    int i = s;
    if ((i & 1) && i < e) {      // head-align to even index for int4 loads
        int2 p = pairs[i];
        float v = half ? 0.f : __int_as_float(p.y);
        const float4 xv = *(const float4*)(xb + (size_t)p.x * B_COLS);
        acc.x = fmaf(v, xv.x, acc.x);
        acc.y = fmaf(v, xv.y, acc.y);
        acc.z = fmaf(v, xv.z, acc.z);
        acc.w = fmaf(v, xv.w, acc.w);
        ++i;
    }
#pragma unroll 4
    for (; i + 1 < e; i += 2) {
        int4 pp = *(const int4*)(&pairs[i]);    // 16B broadcast: entries i, i+1
        int   col = half ? pp.z : pp.x;
        float v   = __int_as_float(half ? pp.w : pp.y);
        const float4 xv = *(const float4*)(xb + (size_t)col * B_COLS);
        acc.x = fmaf(v, xv.x, acc.x);
        acc.y = fmaf(v, xv.y, acc.y);
        acc.z = fmaf(v, xv.z, acc.z);
        acc.w = fmaf(v, xv.w, acc.w);
    }
    if (i < e) {                 // odd tail
        int2 p = pairs[i];
        float v = half ? 0.f : __int_as_float(p.y);
        const float4 xv = *(const float4*)(xb + (size_t)p.x * B_COLS);
        acc.x = fmaf(v, xv.x, acc.x);
        acc.y = fmaf(v, xv.y, acc.y);
        acc.z = fmaf(v, xv.z, acc.z);
        acc.w = fmaf(v, xv.w, acc.w);
    }
    acc.x += __shfl_xor(acc.x, 32, 64);
    acc.y += __shfl_xor(acc.y, 32, 64);
    acc.z += __shfl_xor(acc.z, 32, 64);
    acc.w += __shfl_xor(acc.w, 32, 64);
    if (half == 0)
        *(float4*)(out + (size_t)row * B_COLS + lh * 4) = acc;
}

// ---------- Fallback if workspace too small --------------------------------
__global__ void atomic_spmm_kernel(const int* __restrict__ rows, const int* __restrict__ cols,
                                   const float* __restrict__ vals, int nnz,
                                   const float* __restrict__ x, float* __restrict__ out) {
    long long tid = (long long)blockIdx.x * blockDim.x + threadIdx.x;
    int e = (int)(tid >> 5);
    int g = (int)(tid & 31);
    if (e < nnz) {
        int r = rows[e], c = cols[e];
        float v = vals[e];
        const float4 xv = *(const float4*)(x + (size_t)c * B_COLS + g * 4);
        float* o = out + (size_t)r * B_COLS + g * 4;
        atomicAdd(o + 0, v * xv.x);
        atomicAdd(o + 1, v * xv.y);
        atomicAdd(o + 2, v * xv.z);
        atomicAdd(o + 3, v * xv.w);
    }
}

extern "C" void kernel_launch(void* const* d_in, const int* in_sizes, int n_in,
                              void* d_out, int out_size, void* d_ws, size_t ws_size,
                              hipStream_t stream) {
    const int*   ids  = (const int*)d_in[0];
    const int    nnz  = in_sizes[0] / 2;
    const int*   rows = ids;
    const int*   cols = ids + nnz;
    const float* vals = (const float*)d_in[1];
    const float* x    = (const float*)d_in[2];
    float*       out  = (float*)d_out;

    // ws: perHist[ng*M] | rowTotal[M] | rowStart[M+1] | pad | pairs[nnz]
    size_t fixed_ints = (size_t)M_ROWS + (M_ROWS + 1);
    int ng = 0;
    for (int cand = 256; cand >= 64; cand >>= 1) {
        size_t ints = (size_t)cand * M_ROWS + fixed_ints;
        ints = (ints + 1) & ~(size_t)1;
        if (ws_size >= ints * 4 + (size_t)nnz * 8) { ng = cand; break; }
    }

    if (ng) {
        int*  perHist  = (int*)d_ws;
        int*  rowTotal = perHist + (size_t)ng * M_ROWS;
        int*  rowStart = rowTotal + M_ROWS;
        size_t ints = (size_t)ng * M_ROWS + fixed_ints;
        ints = (ints + 1) & ~(size_t)1;
        int2* pairs = (int2*)((int*)d_ws + ints);
        int chunk = (nnz + ng - 1) / ng;

        hist_kernel<<<ng, 256, 0, stream>>>(rows, nnz, chunk, perHist);
        rowscan_kernel<<<M_ROWS / 1024, 1024, 0, stream>>>(perHist, ng, rowTotal);
        scan_kernel<<<1, 256, 0, stream>>>(rowTotal, rowStart, nnz);
        partition_kernel<<<ng, 256, 0, stream>>>(rows, cols, vals, nnz, chunk,
                                                 perHist, rowStart, pairs);
        spmm_csr_kernel<<<M_ROWS / 4, 256, 0, stream>>>(pairs, rowStart, x, out);
    } else {
        hipMemsetAsync(d_out, 0, (size_t)out_size * sizeof(float), stream);
        long long total = (long long)nnz * 32;
        atomic_spmm_kernel<<<(unsigned)((total + 255) / 256), 256, 0, stream>>>(rows, cols, vals, nnz, x, out);
    }
}

// Round 4
// 181.023 us; speedup vs baseline: 8.1979x; 1.3543x over previous
//
#include <hip/hip_runtime.h>
#include <hip/hip_bf16.h>

// SparseLinear: out[8192,128] = sum over COO entries (r,c,v): out[r,:] += v * x[c,:]
// R4: two-level radix CSR build (512 coarse buckets -> in-LDS per-bucket sort),
// bf16 x copy, quarter-wave spmm (4 entries per gather instruction).

#define M_ROWS 8192
#define B_COLS 128
#define NG   256      // chunks / hist blocks
#define NBK  512      // coarse buckets (row >> 4), 16 rows each
#define CAP  7936     // max entries staged in LDS per bucket (mean 4096, sigma 64 -> +60 sigma)

// ---------- K0: x (fp32) -> bf16 copy, RNE rounding ------------------------
__device__ inline unsigned int f2bf(float f) {
    unsigned int u = __float_as_uint(f);
    return (u + 0x7fffu + ((u >> 16) & 1u)) >> 16;
}
__global__ void __launch_bounds__(256) convx_kernel(const float* __restrict__ x,
                                                    uint4* __restrict__ xb) {
    int i = blockIdx.x * 256 + threadIdx.x;        // 131072 threads, 8 floats each
    const float4* p = (const float4*)x + (size_t)i * 2;
    float4 a = p[0], b = p[1];
    uint4 o;
    o.x = f2bf(a.x) | (f2bf(a.y) << 16);
    o.y = f2bf(a.z) | (f2bf(a.w) << 16);
    o.z = f2bf(b.x) | (f2bf(b.y) << 16);
    o.w = f2bf(b.z) | (f2bf(b.w) << 16);
    xb[i] = o;
}

// ---------- K1: per-chunk bucket histogram + global bucket totals ----------
__global__ void __launch_bounds__(256) hist_kernel(const int* __restrict__ rows, int nnz,
                                                   int chunk, int* __restrict__ perHist,
                                                   int* __restrict__ bucketTotal) {
    __shared__ int h[NBK];
    int t = threadIdx.x, g = blockIdx.x;
    for (int i = t; i < NBK; i += 256) h[i] = 0;
    __syncthreads();
    int s = g * chunk, e = min(s + chunk, nnz);
    for (int i = s + t; i < e; i += 256) atomicAdd(&h[rows[i] >> 4], 1);
    __syncthreads();
    int* dst = perHist + (size_t)g * NBK;          // [g][b]: coalesced writeout
    for (int b = t; b < NBK; b += 256) {
        int c = h[b];
        dst[b] = c;
        if (c) atomicAdd(&bucketTotal[b], c);
    }
}

// ---------- K2: exclusive scan of bucket totals -> bucketStart -------------
__global__ void __launch_bounds__(512) scanbk_kernel(const int* __restrict__ bucketTotal, int nnz,
                                                     int* __restrict__ bucketStart) {
    __shared__ int totals[NBK];
    __shared__ int gbase[64];
    int b = threadIdx.x;
    totals[b] = bucketTotal[b];
    __syncthreads();
    if (b < 64) {
        int gs = 0;
#pragma unroll
        for (int k = 0; k < 8; ++k) gs += totals[b * 8 + k];
        gbase[b] = gs;
    }
    __syncthreads();
    if (b == 0) {
        int acc = 0;
        for (int i = 0; i < 64; ++i) { int c = gbase[i]; gbase[i] = acc; acc += c; }
    }
    __syncthreads();
    int off = gbase[b >> 3];
    for (int k = (b & ~7); k < b; ++k) off += totals[k];
    bucketStart[b] = off;
    if (b == 0) bucketStart[NBK] = nnz;
}

// ---------- K3: per-(chunk,bucket) base = bucketStart + prefix over chunks --
// In place: perHist[g][b] count -> exclusive base. Coalesced (64 consecutive b/wave).
__global__ void __launch_bounds__(64) chunkbase_kernel(int* __restrict__ perHist,
                                                       const int* __restrict__ bucketStart) {
    int b = blockIdx.x * 64 + threadIdx.x;   // grid = NBK/64 = 8
    int acc = bucketStart[b];
    for (int g = 0; g < NG; ++g) {
        size_t idx = (size_t)g * NBK + b;
        int c = perHist[idx];
        perHist[idx] = acc;
        acc += c;
    }
}

// ---------- K4: pass1 scatter into bucket-major order ----------------------
// Each (block,bucket) range is contiguous -> L2 write-combining, no cross-XCD RMW storm.
__global__ void __launch_bounds__(256) scatter1_kernel(const int* __restrict__ rows,
                                                       const int* __restrict__ cols,
                                                       const float* __restrict__ vals,
                                                       int nnz, int chunk,
                                                       const int* __restrict__ perHist,
                                                       int2* __restrict__ pairs) {
    __shared__ int cur[NBK];
    int t = threadIdx.x, g = blockIdx.x;
    const int* base = perHist + (size_t)g * NBK;
    for (int b = t; b < NBK; b += 256) cur[b] = base[b];
    __syncthreads();
    int s = g * chunk, e = min(s + chunk, nnz);
    for (int i = s + t; i < e; i += 256) {
        int r = rows[i];
        int c = cols[i];
        float v = vals[i];
        int pos = atomicAdd(&cur[r >> 4], 1);          // LDS atomic only
        pairs[pos] = make_int2(((r & 15) << 13) | c, __float_as_int(v));
    }
}

// ---------- K5: pass2 per-bucket in-LDS sort -> exact CSR, + rowStart ------
__global__ void __launch_bounds__(256) sort2_kernel(int2* __restrict__ pairs,
                                                    const int* __restrict__ bucketStart,
                                                    int* __restrict__ rowStart, int nnz) {
    __shared__ int2 raw[CAP];          // 62 KB
    __shared__ int h16[16];
    __shared__ int cur16[16];
    int t = threadIdx.x;
    int bkt = blockIdx.x;
    int segS = bucketStart[bkt];
    int n = bucketStart[bkt + 1] - segS;
    if (t < 16) h16[t] = 0;
    __syncthreads();
    int nc = min(n, CAP);              // CAP overflow is +60 sigma -> never for this data
    for (int i = t; i < nc; i += 256) {
        int2 en = pairs[segS + i];     // coalesced
        raw[i] = en;
        atomicAdd(&h16[(en.x >> 13) & 15], 1);
    }
    for (int i = CAP + t; i < n; i += 256)   // theoretical overflow tail (never taken)
        atomicAdd(&h16[(pairs[segS + i].x >> 13) & 15], 1);
    __syncthreads();
    if (t == 0) {
        int acc = segS;
        for (int j = 0; j < 16; ++j) {
            rowStart[bkt * 16 + j] = acc;
            cur16[j] = acc - segS;     // local cursor
            acc += h16[j];
            cur16[j] += (j ? cur16[j] : 0) * 0;  // no-op, keep simple
        }
        // rebuild local exclusive scan properly
        int a2 = 0;
        for (int j = 0; j < 16; ++j) { int c = h16[j]; cur16[j] = a2; a2 += c; }
        if (bkt == NBK - 1) rowStart[M_ROWS] = nnz;
    }
    __syncthreads();
    for (int i = t; i < nc; i += 256) {
        int2 en = raw[i];
        int pos = atomicAdd(&cur16[(en.x >> 13) & 15], 1);
        pairs[segS + pos] = make_int2(en.x & 8191, en.y);   // (col, val), source is LDS -> in-place safe
    }
    for (int i = CAP + t; i < n; i += 256) {
        int2 en = pairs[segS + i];
        int pos = atomicAdd(&cur16[(en.x >> 13) & 15], 1);
        pairs[segS + pos] = make_int2(en.x & 8191, en.y);
    }
}

// ---------- K6: SpMM — wave per row, quarter-wave = 4 entries/iteration ----
__global__ void __launch_bounds__(256) spmm_bf16_kernel(const int2* __restrict__ pairs,
                                                        const int* __restrict__ rowStart,
                                                        const unsigned short* __restrict__ xb,
                                                        float* __restrict__ out) {
    int wave = threadIdx.x >> 6;
    int lane = threadIdx.x & 63;
    int row  = blockIdx.x * 4 + wave;
    int s = rowStart[row];
    int e = rowStart[row + 1];
    int g   = lane >> 4;        // quarter: entry i+g
    int l16 = lane & 15;        // owns bf16 cols l16*8 .. +7
    const unsigned short* xbl = xb + l16 * 8;
    float acc[8];
#pragma unroll
    for (int k = 0; k < 8; ++k) acc[k] = 0.f;

#pragma unroll 2
    for (int i = s; i < e; i += 4) {
        int idx = i + g;
        long long m = (idx < e) ? __builtin_nontemporal_load((const long long*)pairs + idx) : 0LL;
        int col = (int)m;                       // col in [0,8192)
        float v = __int_as_float((int)(m >> 32));
        const uint4 q = *(const uint4*)(xbl + (size_t)col * B_COLS);
#pragma unroll
        for (int k = 0; k < 4; ++k) {
            unsigned int w = (&q.x)[k];
            acc[2 * k]     = fmaf(v, __uint_as_float(w << 16), acc[2 * k]);
            acc[2 * k + 1] = fmaf(v, __uint_as_float(w & 0xffff0000u), acc[2 * k + 1]);
        }
    }
#pragma unroll
    for (int k = 0; k < 8; ++k) {
        acc[k] += __shfl_xor(acc[k], 16, 64);
        acc[k] += __shfl_xor(acc[k], 32, 64);
    }
    if (lane < 16) {
        float* op = out + (size_t)row * B_COLS + l16 * 8;
        *(float4*)op       = make_float4(acc[0], acc[1], acc[2], acc[3]);
        *((float4*)op + 1) = make_float4(acc[4], acc[5], acc[6], acc[7]);
    }
}

// ---------- Fallback if workspace too small --------------------------------
__global__ void atomic_spmm_kernel(const int* __restrict__ rows, const int* __restrict__ cols,
                                   const float* __restrict__ vals, int nnz,
                                   const float* __restrict__ x, float* __restrict__ out) {
    long long tid = (long long)blockIdx.x * blockDim.x + threadIdx.x;
    int e = (int)(tid >> 5);
    int g = (int)(tid & 31);
    if (e < nnz) {
        int r = rows[e], c = cols[e];
        float v = vals[e];
        const float4 xv = *(const float4*)(x + (size_t)c * B_COLS + g * 4);
        float* o = out + (size_t)r * B_COLS + g * 4;
        atomicAdd(o + 0, v * xv.x);
        atomicAdd(o + 1, v * xv.y);
        atomicAdd(o + 2, v * xv.z);
        atomicAdd(o + 3, v * xv.w);
    }
}

extern "C" void kernel_launch(void* const* d_in, const int* in_sizes, int n_in,
                              void* d_out, int out_size, void* d_ws, size_t ws_size,
                              hipStream_t stream) {
    const int*   ids  = (const int*)d_in[0];
    const int    nnz  = in_sizes[0] / 2;
    const int*   rows = ids;
    const int*   cols = ids + nnz;
    const float* vals = (const float*)d_in[1];
    const float* x    = (const float*)d_in[2];
    float*       out  = (float*)d_out;

    // ws (ints): perHist[NG*NBK] | bucketTotal[NBK] | bucketStart[NBK+1] | rowStart[M+1]
    //            | pad-to-16B | xbf[1M bf16 = 512K ints] | pairs[nnz] int2
    size_t o_perHist     = 0;
    size_t o_bucketTotal = o_perHist + (size_t)NG * NBK;
    size_t o_bucketStart = o_bucketTotal + NBK;
    size_t o_rowStart    = o_bucketStart + (NBK + 1);
    size_t o_xbf         = (o_rowStart + (M_ROWS + 1) + 3) & ~(size_t)3;   // 16B align
    size_t o_pairs       = o_xbf + (size_t)M_ROWS * B_COLS / 2;            // bf16 = half an int
    size_t need_bytes    = (o_pairs + (size_t)nnz * 2) * 4;

    if (ws_size >= need_bytes) {
        int*            perHist     = (int*)d_ws + o_perHist;
        int*            bucketTotal = (int*)d_ws + o_bucketTotal;
        int*            bucketStart = (int*)d_ws + o_bucketStart;
        int*            rowStart    = (int*)d_ws + o_rowStart;
        unsigned short* xbf         = (unsigned short*)((int*)d_ws + o_xbf);
        int2*           pairs       = (int2*)((int*)d_ws + o_pairs);
        int chunk = (nnz + NG - 1) / NG;

        hipMemsetAsync(bucketTotal, 0, NBK * sizeof(int), stream);
        convx_kernel<<<(M_ROWS * B_COLS / 8) / 256, 256, 0, stream>>>(x, (uint4*)xbf);
        hist_kernel<<<NG, 256, 0, stream>>>(rows, nnz, chunk, perHist, bucketTotal);
        scanbk_kernel<<<1, 512, 0, stream>>>(bucketTotal, nnz, bucketStart);
        chunkbase_kernel<<<NBK / 64, 64, 0, stream>>>(perHist, bucketStart);
        scatter1_kernel<<<NG, 256, 0, stream>>>(rows, cols, vals, nnz, chunk, perHist, pairs);
        sort2_kernel<<<NBK, 256, 0, stream>>>(pairs, bucketStart, rowStart, nnz);
        spmm_bf16_kernel<<<M_ROWS / 4, 256, 0, stream>>>(pairs, rowStart, xbf, out);
    } else {
        hipMemsetAsync(d_out, 0, (size_t)out_size * sizeof(float), stream);
        long long total = (long long)nnz * 32;
        atomic_spmm_kernel<<<(unsigned)((total + 255) / 256), 256, 0, stream>>>(rows, cols, vals, nnz, x, out);
    }
}

// Round 5
// 143.547 us; speedup vs baseline: 10.3381x; 1.2611x over previous
//
#include <hip/hip_runtime.h>
#include <hip/hip_bf16.h>

// SparseLinear: out[8192,128] = sum over COO entries (r,c,v): out[r,:] += v * x[c,:]
// R5: zero-global-atomic build (transposed perHist + wave-parallel chunk scan),
// scatter to bucket-major, then FUSED per-bucket LDS sort + spmm (bf16 x copy,
// quarter-wave gathers, register accumulation).

#define M_ROWS 8192
#define B_COLS 128
#define NG   256      // chunks (hist/scatter blocks)
#define NBK  512      // coarse buckets (row >> 4), 16 rows each
#define CAP  5120     // LDS-staged entries per bucket; mean 4096, sigma 64 -> +16 sigma

// ---------- K0: x (fp32) -> bf16 copy, RNE rounding ------------------------
__device__ inline unsigned int f2bf(float f) {
    unsigned int u = __float_as_uint(f);
    return (u + 0x7fffu + ((u >> 16) & 1u)) >> 16;
}
__global__ void __launch_bounds__(256) convx_kernel(const float* __restrict__ x,
                                                    uint4* __restrict__ xb) {
    int i = blockIdx.x * 256 + threadIdx.x;        // 131072 threads, 8 floats each
    const float4* p = (const float4*)x + (size_t)i * 2;
    float4 a = p[0], b = p[1];
    uint4 o;
    o.x = f2bf(a.x) | (f2bf(a.y) << 16);
    o.y = f2bf(a.z) | (f2bf(a.w) << 16);
    o.z = f2bf(b.x) | (f2bf(b.y) << 16);
    o.w = f2bf(b.z) | (f2bf(b.w) << 16);
    xb[i] = o;
}

// ---------- K1: per-chunk bucket histogram, transposed write [b][g] --------
__global__ void __launch_bounds__(256) histT_kernel(const int* __restrict__ rows, int nnz,
                                                    int chunk, int* __restrict__ perHistT) {
    __shared__ int h[NBK];
    int t = threadIdx.x, g = blockIdx.x;
    for (int i = t; i < NBK; i += 256) h[i] = 0;
    __syncthreads();
    int s = g * chunk, e = min(s + chunk, nnz);
    for (int i = s + t; i < e; i += 256) atomicAdd(&h[rows[i] >> 4], 1);
    __syncthreads();
    for (int b = t; b < NBK; b += 256) perHistT[(size_t)b * NG + g] = h[b];
}

// ---------- K2: per-bucket exclusive scan over chunks (wave-parallel) ------
// One wave per bucket. Lane loads 4 counts (int4, coalesced), shfl-scan across
// 64 lanes, write back exclusive bases; lane 63 emits the bucket total.
__global__ void __launch_bounds__(512) chunkscan_kernel(int* __restrict__ perHistT,
                                                        int* __restrict__ totals) {
    int wave = threadIdx.x >> 6, lane = threadIdx.x & 63;
    int b = blockIdx.x * 8 + wave;                 // grid = NBK/8 = 64
    int4* p = (int4*)(perHistT + (size_t)b * NG) + lane;
    int4 c = *p;
    int s = c.x + c.y + c.z + c.w;
    int incl = s;
#pragma unroll
    for (int d = 1; d < 64; d <<= 1) {
        int up = __shfl_up(incl, d, 64);
        if (lane >= d) incl += up;
    }
    int base = incl - s;                           // exclusive over lanes
    int4 o;
    o.x = base;
    o.y = base + c.x;
    o.z = o.y + c.y;
    o.w = o.z + c.z;
    *p = o;
    if (lane == 63) totals[b] = incl;
}

// ---------- K3: exclusive scan of bucket totals -> bucketStart -------------
__global__ void __launch_bounds__(512) scanbk_kernel(const int* __restrict__ totals, int nnz,
                                                     int* __restrict__ bucketStart) {
    __shared__ int tsh[NBK];
    __shared__ int gbase[64];
    int b = threadIdx.x;
    tsh[b] = totals[b];
    __syncthreads();
    if (b < 64) {
        int gs = 0;
#pragma unroll
        for (int k = 0; k < 8; ++k) gs += tsh[b * 8 + k];
        gbase[b] = gs;
    }
    __syncthreads();
    if (b == 0) {
        int acc = 0;
        for (int i = 0; i < 64; ++i) { int c = gbase[i]; gbase[i] = acc; acc += c; }
    }
    __syncthreads();
    int off = gbase[b >> 3];
    for (int k = (b & ~7); k < b; ++k) off += tsh[k];
    bucketStart[b] = off;
    if (b == 0) bucketStart[NBK] = nnz;
}

// ---------- K4: scatter into bucket-major order (LDS cursors only) ---------
__global__ void __launch_bounds__(256) scatter1_kernel(const int* __restrict__ rows,
                                                       const int* __restrict__ cols,
                                                       const float* __restrict__ vals,
                                                       int nnz, int chunk,
                                                       const int* __restrict__ perHistT,
                                                       const int* __restrict__ bucketStart,
                                                       int2* __restrict__ pairs) {
    __shared__ int cur[NBK];
    int t = threadIdx.x, g = blockIdx.x;
    for (int b = t; b < NBK; b += 256)
        cur[b] = bucketStart[b] + perHistT[(size_t)b * NG + g];
    __syncthreads();
    int s = g * chunk, e = min(s + chunk, nnz);
    for (int i = s + t; i < e; i += 256) {
        int r = rows[i];
        int c = cols[i];
        float v = vals[i];
        int pos = atomicAdd(&cur[r >> 4], 1);      // LDS atomic only
        pairs[pos] = make_int2(((r & 15) << 13) | c, __float_as_int(v));
    }
}

// ---------- K5: FUSED per-bucket sort + spmm -------------------------------
// 1024 threads = 16 waves = 16 rows. Stage bucket entries in registers while
// building a 16-bin hist, scatter sorted into LDS, then wave-per-row spmm:
// quarter g handles entry i+g, lane l16 owns bf16 cols l16*8..+7.
__global__ void __launch_bounds__(1024) sortspmm_kernel(const int2* __restrict__ pairs,
                                                        const int* __restrict__ bucketStart,
                                                        const unsigned short* __restrict__ xb,
                                                        float* __restrict__ out) {
    __shared__ int2 sorted[CAP];                   // 40 KB
    __shared__ int h16[16];
    __shared__ int cur16[16];
    __shared__ int rs[17];
    int t = threadIdx.x;
    int bkt = blockIdx.x;
    int segS = bucketStart[bkt];
    int n = bucketStart[bkt + 1] - segS;
    int nc = min(n, CAP);
    if (t < 16) h16[t] = 0;
    __syncthreads();

    int2 buf[5];                                   // CAP = 5 * 1024
#pragma unroll
    for (int k = 0; k < 5; ++k) {
        int i = t + 1024 * k;
        if (i < nc) {
            int2 en = pairs[segS + i];             // coalesced
            buf[k] = en;
            atomicAdd(&h16[(en.x >> 13) & 15], 1);
        }
    }
    __syncthreads();
    if (t == 0) {
        int acc = 0;
#pragma unroll
        for (int j = 0; j < 16; ++j) { rs[j] = acc; cur16[j] = acc; acc += h16[j]; }
        rs[16] = acc;
    }
    __syncthreads();
#pragma unroll
    for (int k = 0; k < 5; ++k) {
        int i = t + 1024 * k;
        if (i < nc) {
            int2 en = buf[k];
            int pos = atomicAdd(&cur16[(en.x >> 13) & 15], 1);
            sorted[pos] = make_int2(en.x & 8191, en.y);
        }
    }
    __syncthreads();

    int wave = t >> 6;                             // = row within bucket
    int lane = t & 63;
    int g = lane >> 4, l16 = lane & 15;
    const unsigned short* xbl = xb + l16 * 8;
    int b0 = rs[wave], e0 = rs[wave + 1];
    float acc[8];
#pragma unroll
    for (int k = 0; k < 8; ++k) acc[k] = 0.f;

#pragma unroll 2
    for (int i = b0; i < e0; i += 4) {
        int idx = i + g;
        int2 en = (idx < e0) ? sorted[idx] : make_int2(0, 0);   // ds_read_b64 broadcast/quarter
        float v = (idx < e0) ? __int_as_float(en.y) : 0.f;
        const uint4 q = *(const uint4*)(xbl + (size_t)en.x * B_COLS);
#pragma unroll
        for (int k = 0; k < 4; ++k) {
            unsigned int w = (&q.x)[k];
            acc[2 * k]     = fmaf(v, __uint_as_float(w << 16), acc[2 * k]);
            acc[2 * k + 1] = fmaf(v, __uint_as_float(w & 0xffff0000u), acc[2 * k + 1]);
        }
    }
    // overflow tail (n > CAP): correct but never taken for this data
    for (int i = CAP; i < n; ++i) {
        int2 en = pairs[segS + i];
        if (((en.x >> 13) & 15) == wave) {
            float v = (g == 0) ? __int_as_float(en.y) : 0.f;
            const uint4 q = *(const uint4*)(xbl + (size_t)(en.x & 8191) * B_COLS);
#pragma unroll
            for (int k = 0; k < 4; ++k) {
                unsigned int w = (&q.x)[k];
                acc[2 * k]     = fmaf(v, __uint_as_float(w << 16), acc[2 * k]);
                acc[2 * k + 1] = fmaf(v, __uint_as_float(w & 0xffff0000u), acc[2 * k + 1]);
            }
        }
    }
#pragma unroll
    for (int k = 0; k < 8; ++k) {
        acc[k] += __shfl_xor(acc[k], 16, 64);
        acc[k] += __shfl_xor(acc[k], 32, 64);
    }
    if (lane < 16) {
        float* op = out + ((size_t)(bkt * 16 + wave)) * B_COLS + l16 * 8;
        *(float4*)op       = make_float4(acc[0], acc[1], acc[2], acc[3]);
        *((float4*)op + 1) = make_float4(acc[4], acc[5], acc[6], acc[7]);
    }
}

// ---------- Fallback if workspace too small --------------------------------
__global__ void atomic_spmm_kernel(const int* __restrict__ rows, const int* __restrict__ cols,
                                   const float* __restrict__ vals, int nnz,
                                   const float* __restrict__ x, float* __restrict__ out) {
    long long tid = (long long)blockIdx.x * blockDim.x + threadIdx.x;
    int e = (int)(tid >> 5);
    int g = (int)(tid & 31);
    if (e < nnz) {
        int r = rows[e], c = cols[e];
        float v = vals[e];
        const float4 xv = *(const float4*)(x + (size_t)c * B_COLS + g * 4);
        float* o = out + (size_t)r * B_COLS + g * 4;
        atomicAdd(o + 0, v * xv.x);
        atomicAdd(o + 1, v * xv.y);
        atomicAdd(o + 2, v * xv.z);
        atomicAdd(o + 3, v * xv.w);
    }
}

extern "C" void kernel_launch(void* const* d_in, const int* in_sizes, int n_in,
                              void* d_out, int out_size, void* d_ws, size_t ws_size,
                              hipStream_t stream) {
    const int*   ids  = (const int*)d_in[0];
    const int    nnz  = in_sizes[0] / 2;
    const int*   rows = ids;
    const int*   cols = ids + nnz;
    const float* vals = (const float*)d_in[1];
    const float* x    = (const float*)d_in[2];
    float*       out  = (float*)d_out;

    // ws (ints): perHistT[NBK*NG] | totals[NBK] | bucketStart[NBK+1]
    //            | pad-to-16B | xbf[1M bf16 = 512K ints] | pairs[nnz] int2
    size_t o_perHistT    = 0;
    size_t o_totals      = o_perHistT + (size_t)NBK * NG;
    size_t o_bucketStart = o_totals + NBK;
    size_t o_xbf         = (o_bucketStart + (NBK + 1) + 3) & ~(size_t)3;   // 16B align
    size_t o_pairs       = o_xbf + (size_t)M_ROWS * B_COLS / 2;
    size_t need_bytes    = (o_pairs + (size_t)nnz * 2) * 4;

    if (ws_size >= need_bytes) {
        int*            perHistT    = (int*)d_ws + o_perHistT;
        int*            totals      = (int*)d_ws + o_totals;
        int*            bucketStart = (int*)d_ws + o_bucketStart;
        unsigned short* xbf         = (unsigned short*)((int*)d_ws + o_xbf);
        int2*           pairs       = (int2*)((int*)d_ws + o_pairs);
        int chunk = (nnz + NG - 1) / NG;

        convx_kernel<<<(M_ROWS * B_COLS / 8) / 256, 256, 0, stream>>>(x, (uint4*)xbf);
        histT_kernel<<<NG, 256, 0, stream>>>(rows, nnz, chunk, perHistT);
        chunkscan_kernel<<<NBK / 8, 512, 0, stream>>>(perHistT, totals);
        scanbk_kernel<<<1, 512, 0, stream>>>(totals, nnz, bucketStart);
        scatter1_kernel<<<NG, 256, 0, stream>>>(rows, cols, vals, nnz, chunk,
                                                perHistT, bucketStart, pairs);
        sortspmm_kernel<<<NBK, 1024, 0, stream>>>(pairs, bucketStart, xbf, out);
    } else {
        hipMemsetAsync(d_out, 0, (size_t)out_size * sizeof(float), stream);
        long long total = (long long)nnz * 32;
        atomic_spmm_kernel<<<(unsigned)((total + 255) / 256), 256, 0, stream>>>(rows, cols, vals, nnz, x, out);
    }
}